// Round 7
// baseline (162.743 us; speedup 1.0000x reference)
//
#include <hip/hip_runtime.h>

#define N_FEAT 1024
#define N_LAYER 4
#define ROWS_PER_WAVE 4   // 2 iterations x 2 rows
#define PAIR 2

// Algebra: xi = A_i*x0 + C_i, C_i = sum_{j<i} b_j (row-independent).
//   p_i = <x0,w_i>, e_i = <C_i,w_i>; A_{i+1} = A_i*(1+p_i) + e_i;
//   out = A_4*x0 + csum.
//
// Copy-shaped high-occupancy experiment. Evidence so far: all 8-waves/CU
// structures (regs R0, DMA+barrier R4, DMA+vmcnt R5) sit at 29-31us
// (~4.4 TB/s mixed); copy ubench does 6.29 TB/s. Queue depth (Little's law)
// and VALU (~10%) are ruled out; choreography is ruled out (R4==R5). The
// untested copy property is high resident-wave count with long-lived blocks
// and PLAIN register loads (no LDS-DMA path — R4-R6 all used it; it may
// itself cap at ~4.4 TB/s). Here:
//  - w (16KB) + csum (4KB) live in LDS, written redundantly by every wave
//    (identical bits -> benign race, wave reads own writes, ZERO barriers).
//  - per-thread state: current pair + prefetched next pair (~110 VGPR)
//    -> __launch_bounds__(256,4) = 4 blocks/CU = 16 waves/CU.
//  - grid 1024 = 4 x 256 CU exactly: all blocks resident at t=0, no ramp.
//  - per wave: 4 rows = 2 iterations of 2 rows; next-pair loads issued
//    before current-pair compute (depth-1 register pipeline).
// ds_read pattern: 64 lanes x 16B consecutive = conflict-free (m136).
__global__ __launch_bounds__(256, 4) void crossnet_kernel(
    const float* __restrict__ x,
    const float* __restrict__ weight_w,
    const float* __restrict__ weight_b,
    float* __restrict__ out,
    int n_rows) {
  const int wave = threadIdx.x >> 6;   // 0..3
  const int lane = threadIdx.x & 63;

  __shared__ float4 w_lds[N_LAYER * 256];  // [layer][col] 16 KB
  __shared__ float4 csum_lds[256];         // 4 KB

  // ---- preamble (per wave, redundant, barrier-free): w->LDS, csum->LDS, e ----
  float e[N_LAYER] = {0.f, 0.f, 0.f, 0.f};
#pragma unroll
  for (int c = 0; c < 4; ++c) {
    const int col = c * 64 + lane;
    float4 wv[N_LAYER];
#pragma unroll
    for (int i = 0; i < N_LAYER; ++i) {
      wv[i] = ((const float4*)(weight_w + i * N_FEAT))[col];
      w_lds[i * 256 + col] = wv[i];
    }
    float4 cum = make_float4(0.f, 0.f, 0.f, 0.f);
#pragma unroll
    for (int i = 0; i < N_LAYER; ++i) {
      if (i > 0)
        e[i] += cum.x * wv[i].x + cum.y * wv[i].y +
                cum.z * wv[i].z + cum.w * wv[i].w;
      const float4 b = ((const float4*)(weight_b + i * N_FEAT))[col];
      cum.x += b.x; cum.y += b.y; cum.z += b.z; cum.w += b.w;
    }
    csum_lds[col] = cum;
  }
#pragma unroll
  for (int off = 32; off > 0; off >>= 1)
#pragma unroll
    for (int i = 1; i < N_LAYER; ++i) e[i] += __shfl_xor(e[i], off, 64);

  // ---- row range for this wave: 4 contiguous rows ----
  const int g = blockIdx.x * 4 + wave;
  const int row_base = g * ROWS_PER_WAVE;
  if (row_base >= n_rows) return;

  const float4* xq = (const float4*)x;   // row stride = 256 float4
  float4* oq = (float4*)out;

  // prologue: load pair 0 (rows row_base, row_base+1)
  float4 xv[PAIR][4];
#pragma unroll
  for (int r = 0; r < PAIR; ++r)
#pragma unroll
    for (int c = 0; c < 4; ++c)
      xv[r][c] = xq[(size_t)(row_base + r) * 256 + c * 64 + lane];

#pragma unroll
  for (int t = 0; t < ROWS_PER_WAVE / PAIR; ++t) {
    const int pr = row_base + t * PAIR;

    // issue next pair's 8 loads before computing this pair
    float4 nxt[PAIR][4];
    if (t + 1 < ROWS_PER_WAVE / PAIR) {
#pragma unroll
      for (int r = 0; r < PAIR; ++r)
#pragma unroll
        for (int c = 0; c < 4; ++c)
          nxt[r][c] = xq[(size_t)(pr + PAIR + r) * 256 + c * 64 + lane];
    }

    // ---- dot phase: w from LDS (conflict-free b128), xv in regs ----
    float p[PAIR * N_LAYER];
#pragma unroll
    for (int k = 0; k < PAIR * N_LAYER; ++k) p[k] = 0.f;
#pragma unroll
    for (int c = 0; c < 4; ++c) {
      const int col = c * 64 + lane;
#pragma unroll
      for (int i = 0; i < N_LAYER; ++i) {
        const float4 wv = w_lds[i * 256 + col];
#pragma unroll
        for (int r = 0; r < PAIR; ++r) {
          p[r * N_LAYER + i] += xv[r][c].x * wv.x + xv[r][c].y * wv.y +
                                xv[r][c].z * wv.z + xv[r][c].w * wv.w;
        }
      }
    }

    // ---- butterfly: 8 p-values, 6 steps ----
#pragma unroll
    for (int off = 32; off > 0; off >>= 1)
#pragma unroll
      for (int k = 0; k < PAIR * N_LAYER; ++k) p[k] += __shfl_xor(p[k], off, 64);

    // ---- recurrence + store (csum from LDS) ----
#pragma unroll
    for (int r = 0; r < PAIR; ++r) {
      float A = 1.f;
#pragma unroll
      for (int i = 0; i < N_LAYER; ++i)
        A += A * p[r * N_LAYER + i] + e[i];
#pragma unroll
      for (int c = 0; c < 4; ++c) {
        const int col = c * 64 + lane;
        const float4 cs = csum_lds[col];
        float4 o;
        o.x = fmaf(xv[r][c].x, A, cs.x);
        o.y = fmaf(xv[r][c].y, A, cs.y);
        o.z = fmaf(xv[r][c].z, A, cs.z);
        o.w = fmaf(xv[r][c].w, A, cs.w);
        oq[(size_t)(pr + r) * 256 + col] = o;
      }
    }

    // rotate pipeline
    if (t + 1 < ROWS_PER_WAVE / PAIR) {
#pragma unroll
      for (int r = 0; r < PAIR; ++r)
#pragma unroll
        for (int c = 0; c < 4; ++c)
          xv[r][c] = nxt[r][c];
    }
  }
}

extern "C" void kernel_launch(void* const* d_in, const int* in_sizes, int n_in,
                              void* d_out, int out_size, void* d_ws, size_t ws_size,
                              hipStream_t stream) {
  const float* x = (const float*)d_in[0];
  const float* ww = (const float*)d_in[1];
  const float* wb = (const float*)d_in[2];
  float* out = (float*)d_out;

  const int n_rows = in_sizes[0] / N_FEAT;            // 16384
  const int rows_per_block = 4 * ROWS_PER_WAVE;       // 16
  const int n_blocks = (n_rows + rows_per_block - 1) / rows_per_block;  // 1024
  crossnet_kernel<<<n_blocks, 256, 0, stream>>>(x, ww, wb, out, n_rows);
}